// Round 3
// baseline (41.657 us; speedup 1.0000x reference)
//
#include <hip/hip_runtime.h>
#include <hip/hip_bf16.h>

#define W_OUT 768
#define H_OUT 768
#define N_BOXES 128

// One block (256 thr) per box b. scores[b] = max conf over pixels contained in
// b and in no other valid box. lane (tid&63) walks x contiguously (coalesced
// conf loads); ty (tid>>6) strides rows by 4. Overlap candidates are a 128-bit
// ballot mask (computed per-wave, no sync/atomics), pre-filtered per row by
// the y-test, so the per-pixel loop touches only ~2 set bits with one x-test
// each. No integer div/mod anywhere in the hot loop. One plain store per box.
__global__ __launch_bounds__(256) void box_score_kernel(
    const float* __restrict__ conf,
    const float* __restrict__ boxes,
    float* __restrict__ scores) {
    __shared__ float4 sbox[N_BOXES];
    __shared__ float wmax[4];

    const int tid = threadIdx.x;
    const int lane = tid & 63;
    const int ty = tid >> 6;
    const int b = blockIdx.x;

    const float4* b4 = (const float4*)boxes;
    const float4 me = b4[b];                       // uniform -> scalar load
    const bool mevalid = (me.z - me.x) * (me.w - me.y) > 0.0f;
    if (!mevalid) {
        if (tid == 0) scores[b] = 0.0f;
        return;                                    // block-uniform exit
    }

    if (tid < N_BOXES) sbox[tid] = b4[tid];        // stage all boxes

    // 128-bit overlap mask, built redundantly in every wave (no cross-wave
    // exchange needed): lane tests boxes lane and 64+lane against our rect.
    float4 oa = b4[lane];
    float4 ob = b4[64 + lane];
    bool ia = (oa.z - oa.x) * (oa.w - oa.y) > 0.0f &&
              oa.x <= me.z && oa.z >= me.x && oa.y <= me.w && oa.w >= me.y;
    bool ib = (ob.z - ob.x) * (ob.w - ob.y) > 0.0f &&
              ob.x <= me.z && ob.z >= me.x && ob.y <= me.w && ob.w >= me.y;
    unsigned long long m0 = __ballot(ia);
    unsigned long long m1 = __ballot(ib);
    if (b < 64) m0 &= ~(1ull << b);
    else        m1 &= ~(1ull << (b - 64));
    __syncthreads();                               // sbox ready

    // Conservative integer pixel bounds (exact float predicate inside).
    const int x0 = max(0, (int)floorf(me.x * 0.5f - 0.5f) - 1);
    const int x1 = min(W_OUT - 1, (int)ceilf(me.z * 0.5f) + 1);
    const int y0 = max(0, (int)floorf(me.y * 0.5f - 0.5f) - 1);
    const int y1 = min(H_OUT - 1, (int)ceilf(me.w * 0.5f) + 1);

    float lmax = 0.0f;
    for (int yy = y0 + ty; yy <= y1; yy += 4) {    // yy uniform within wave
        const float py = (yy + 0.5f) * 2.0f;       // bit-exact vs reference
        if (py < me.y || py > me.w) continue;

        // Row-filtered overlap masks (wave-uniform bit iteration).
        unsigned long long r0 = 0, r1 = 0;
        unsigned long long t = m0;
        while (t) {
            int j = __ffsll(t) - 1; t &= t - 1;
            float4 o = sbox[j];                    // uniform -> LDS broadcast
            if (py >= o.y && py <= o.w) r0 |= 1ull << j;
        }
        t = m1;
        while (t) {
            int j = __ffsll(t) - 1; t &= t - 1;
            float4 o = sbox[64 + j];
            if (py >= o.y && py <= o.w) r1 |= 1ull << j;
        }

        const float* crow = conf + yy * W_OUT;
        for (int xx = x0 + lane; xx <= x1; xx += 64) {
            const float px = (xx + 0.5f) * 2.0f;
            if (px < me.x || px > me.z) continue;
            bool excl = true;
            t = r0;
            while (t) {
                int j = __ffsll(t) - 1; t &= t - 1;
                float4 o = sbox[j];
                if (px >= o.x && px <= o.z) { excl = false; break; }
            }
            if (excl) {
                t = r1;
                while (t) {
                    int j = __ffsll(t) - 1; t &= t - 1;
                    float4 o = sbox[64 + j];
                    if (px >= o.x && px <= o.z) { excl = false; break; }
                }
            }
            if (excl) lmax = fmaxf(lmax, crow[xx]); // coalesced within wave
        }
    }

    // Wave max-reduce (butterfly), then cross-wave via 4-slot LDS.
    for (int off = 32; off > 0; off >>= 1)
        lmax = fmaxf(lmax, __shfl_xor(lmax, off));
    if (lane == 0) wmax[ty] = lmax;
    __syncthreads();
    if (tid == 0)
        scores[b] = fmaxf(fmaxf(wmax[0], wmax[1]), fmaxf(wmax[2], wmax[3]));
}

extern "C" void kernel_launch(void* const* d_in, const int* in_sizes, int n_in,
                              void* d_out, int out_size, void* d_ws, size_t ws_size,
                              hipStream_t stream) {
    const float* conf = (const float*)d_in[0];     // (1, 768, 768) f32
    const float* boxes = (const float*)d_in[1];    // (128, 4) f32
    float* scores = (float*)d_out;                 // (128,) f32

    box_score_kernel<<<N_BOXES, 256, 0, stream>>>(conf, boxes, scores);
}

// Round 4
// 12.460 us; speedup vs baseline: 3.3433x; 3.3433x over previous
//
#include <hip/hip_runtime.h>
#include <hip/hip_bf16.h>

#define W_OUT 768
#define H_OUT 768
#define N_BOXES 128

// Kernel 1 — one block per image row (768 blocks x 256 threads = 12 waves/CU).
// Each thread owns 3 pixels of the row (x = tid, tid+256, tid+512; 768=3*256).
// Row's candidate boxes = 128-bit ballot mask (valid && y-contained), ~7 bits.
// Box-outer / pixel-inner: each set bit costs ONE wave-uniform LDS broadcast
// read, testing all 3 pixels. count==1 pixels max into 128 per-block LDS
// slots (LDS atomics — round 1's global-atomic serialization eliminated).
// Block then writes its 128-slot row-max vector to workspace (coalesced).
__global__ __launch_bounds__(256) void row_owner_kernel(
    const float* __restrict__ conf,
    const float* __restrict__ boxes,
    float* __restrict__ partial) {
    __shared__ float4 sbox[N_BOXES];
    __shared__ unsigned int slot[N_BOXES];
    __shared__ unsigned long long masks[2];

    const int tid = threadIdx.x;
    const int y = blockIdx.x;

    // Issue the row's conf loads first — HBM latency hides under LDS setup.
    const float* crow = conf + y * W_OUT;
    const float c0 = crow[tid];
    const float c1 = crow[tid + 256];
    const float c2 = crow[tid + 512];

    const float4* b4 = (const float4*)boxes;
    if (tid < N_BOXES) {
        float4 o = b4[tid];
        sbox[tid] = o;
        slot[tid] = 0u;
        const float py = (y + 0.5f) * 2.0f;          // bit-exact vs reference
        bool in = (o.z - o.x) * (o.w - o.y) > 0.0f && py >= o.y && py <= o.w;
        unsigned long long m = __ballot(in);          // waves 0,1 fully active
        if ((tid & 63) == 0) masks[tid >> 6] = m;
    }
    __syncthreads();

    const unsigned long long m0 = masks[0];
    const unsigned long long m1 = masks[1];

    const float px0 = (tid + 0.5f) * 2.0f;
    const float px1 = (tid + 256 + 0.5f) * 2.0f;
    const float px2 = (tid + 512 + 0.5f) * 2.0f;
    int cnt0 = 0, cnt1 = 0, cnt2 = 0;
    int own0 = -1, own1 = -1, own2 = -1;

    unsigned long long t = m0;
    while (t) {
        int j = __ffsll(t) - 1; t &= t - 1;
        float4 o = sbox[j];                           // uniform -> broadcast
        if (px0 >= o.x && px0 <= o.z) { cnt0++; if (own0 < 0) own0 = j; }
        if (px1 >= o.x && px1 <= o.z) { cnt1++; if (own1 < 0) own1 = j; }
        if (px2 >= o.x && px2 <= o.z) { cnt2++; if (own2 < 0) own2 = j; }
    }
    t = m1;
    while (t) {
        int j = __ffsll(t) - 1; t &= t - 1;
        float4 o = sbox[64 + j];
        if (px0 >= o.x && px0 <= o.z) { cnt0++; if (own0 < 0) own0 = 64 + j; }
        if (px1 >= o.x && px1 <= o.z) { cnt1++; if (own1 < 0) own1 = 64 + j; }
        if (px2 >= o.x && px2 <= o.z) { cnt2++; if (own2 < 0) own2 = 64 + j; }
    }

    // Exclusive pixels feed per-box LDS max (uint-bit order == float order
    // for non-negative conf). ~1.2 atomics/thread, 128 slots: no hot spot.
    if (cnt0 == 1) atomicMax(&slot[own0], __float_as_uint(c0));
    if (cnt1 == 1) atomicMax(&slot[own1], __float_as_uint(c1));
    if (cnt2 == 1) atomicMax(&slot[own2], __float_as_uint(c2));
    __syncthreads();

    if (tid < N_BOXES)
        partial[y * N_BOXES + tid] = __uint_as_float(slot[tid]);
}

// Kernel 2 — one block per box: max over the 768 per-row partials (column b
// of the 768x128 workspace, L2-resident), block max-reduce, one plain store.
__global__ __launch_bounds__(256) void reduce_kernel(
    const float* __restrict__ partial,
    float* __restrict__ scores) {
    __shared__ float wmax[4];
    const int b = blockIdx.x;
    const int tid = threadIdx.x;

    float m = fmaxf(fmaxf(partial[tid * N_BOXES + b],
                          partial[(tid + 256) * N_BOXES + b]),
                    partial[(tid + 512) * N_BOXES + b]);
    for (int off = 32; off > 0; off >>= 1)
        m = fmaxf(m, __shfl_xor(m, off));
    if ((tid & 63) == 0) wmax[tid >> 6] = m;
    __syncthreads();
    if (tid == 0)
        scores[b] = fmaxf(fmaxf(wmax[0], wmax[1]), fmaxf(wmax[2], wmax[3]));
}

extern "C" void kernel_launch(void* const* d_in, const int* in_sizes, int n_in,
                              void* d_out, int out_size, void* d_ws, size_t ws_size,
                              hipStream_t stream) {
    const float* conf = (const float*)d_in[0];     // (1, 768, 768) f32
    const float* boxes = (const float*)d_in[1];    // (128, 4) f32
    float* scores = (float*)d_out;                 // (128,) f32
    float* partial = (float*)d_ws;                 // 768*128*4 B = 384 KiB

    row_owner_kernel<<<H_OUT, 256, 0, stream>>>(conf, boxes, partial);
    reduce_kernel<<<N_BOXES, 256, 0, stream>>>(partial, scores);
}